// Round 11
// baseline (65.597 us; speedup 1.0000x reference)
//
#include <hip/hip_runtime.h>

#define WALK_LEN 40
#define WINDOW   5
#define NPAIRS   370
#define BATCHSZ  512
#define NEGK     5
#define NPOS     (BATCHSZ * NPAIRS)        // 189440
#define EMB      128
#define THREADS  512
#define GROUPS   (THREADS / 8)             // 64 8-lane groups
#define HALFP    185                       // pairs per block (2 blocks/batch)
#define NBLOCKS  (BATCHSZ * 2)             // 1024

struct PairTab { short src[NPAIRS]; short dst[NPAIRS]; };

constexpr PairTab make_pairs() {
    PairTab t{};
    int k = 0;
    for (int i = 0; i < WALK_LEN; ++i) {
        int lo = (i - WINDOW > 0) ? (i - WINDOW) : 0;
        for (int j = lo; j < i; ++j) { t.src[k] = (short)j; t.dst[k] = (short)i; ++k; }
        int hi = (i + 1 + WINDOW < WALK_LEN) ? (i + 1 + WINDOW) : WALK_LEN;
        for (int j = i + 1; j < hi; ++j) { t.src[k] = (short)j; t.dst[k] = (short)i; ++k; }
    }
    return t;
}

__constant__ PairTab g_pairs = make_pairs();

// fast softplus: log(1+e^x); |err| ~1e-7 for x in [-6,6]
__device__ __forceinline__ float softplus_fast(float x) {
    return __logf(1.0f + __expf(x));
}

// 8-lane-group butterfly sum: xor1/xor2 via quad_perm DPP (VALU-only),
// xor4 via one ds_swizzle.
template <int CTRL>
__device__ __forceinline__ float dpp_qperm_add(float x) {
    int y = __builtin_amdgcn_update_dpp(0, __float_as_int(x), CTRL, 0xF, 0xF, true);
    return x + __int_as_float(y);
}
__device__ __forceinline__ float grp8_sum(float d) {
    d = dpp_qperm_add<0xB1>(d);    // quad_perm [1,0,3,2] == xor 1
    d = dpp_qperm_add<0x4E>(d);    // quad_perm [2,3,0,1] == xor 2
    int y = __builtin_amdgcn_ds_swizzle(__float_as_int(d), 0x101F); // xor 4
    return d + __int_as_float(y);
}

__device__ __forceinline__ float dot4(float4 a, float4 c) {
    return (a.x * c.x + a.y * c.y) + (a.z * c.z + a.w * c.w);
}
// 16-elem tree dot: 4 parallel dot4 chains
#define DOT16(A0, A1, A2, A3, C0, C1, C2, C3) \
    ((dot4(A0, C0) + dot4(A1, C1)) + (dot4(A2, C2) + dot4(A3, C3)))

// lane l of an 8-lane group owns float4 indices l, l+8, l+16, l+24 of a row
#define LOAD_ROW(v0, v1, v2, v3, baseptr)            \
    do {                                             \
        const float4* _r = (baseptr);                \
        v0 = _r[lane8];      v1 = _r[lane8 + 8];     \
        v2 = _r[lane8 + 16]; v3 = _r[lane8 + 24];    \
    } while (0)

// Fused single-phase kernel: one block = half a batch (185 pairs).
// Stage the batch's 40 node + 40 ctx f32 rows in LDS; positives + neg-src
// read LDS; neg-dst rows read ctxE directly (L3-resident), double-buffered.
__global__ __launch_bounds__(THREADS) void dw_fused(
    const int*   __restrict__ walk,     // [BATCHSZ*WALK_LEN]
    const int*   __restrict__ negdst,   // [NPOS*NEGK] -> flat-walk positions
    const float* __restrict__ nodeE,
    const float* __restrict__ ctxE,
    float*       __restrict__ out)      // [1], pre-zeroed by memset
{
    __shared__ float sN[WALK_LEN][EMB];   // 20 KB
    __shared__ float sC[WALK_LEN][EMB];   // 20 KB
    __shared__ int   swalk[WALK_LEN];
    __shared__ float wsum[THREADS / 64];

    const int b    = blockIdx.x >> 1;
    const int half = blockIdx.x & 1;
    const int tid  = threadIdx.x;

    if (tid < WALK_LEN) swalk[tid] = walk[b * WALK_LEN + tid];
    __syncthreads();

    for (int u = tid; u < WALK_LEN * 32; u += THREADS) {
        const int r = u >> 5, l = u & 31;
        const size_t row = (size_t)swalk[r] * EMB;
        ((float4*)sN)[u] = *((const float4*)(nodeE + row) + l);
        ((float4*)sC)[u] = *((const float4*)(ctxE  + row) + l);
    }
    __syncthreads();

    const int lane8 = tid & 7;
    const int grp   = tid >> 3;           // 0..63
    const int jbase = half * HALFP;
    float acc = 0.0f;

    #pragma unroll 1
    for (int it = 0; it < 3; ++it) {
        const int jj = it * GROUPS + grp;           // 0..191
        if (jj < HALFP) {
            const int j = jbase + jj;
            const int p = b * NPAIRS + j;
            const int sj = g_pairs.src[j];
            const int dj = g_pairs.dst[j];

            // 5 independent 2-deep index chains, issued up front
            const int* nb = negdst + p * NEGK;
            const int q0 = nb[0], q1 = nb[1], q2 = nb[2], q3 = nb[3], q4 = nb[4];
            const int r0 = walk[q0], r1 = walk[q1], r2 = walk[q2],
                      r3 = walk[q3], r4 = walk[q4];

            // double-buffered neg ctx rows (f32, direct from table)
            float4 x0, x1, x2, x3;   // buffer A
            float4 y0, y1, y2, y3;   // buffer B
            LOAD_ROW(x0, x1, x2, x3, (const float4*)(ctxE + (size_t)r0 * EMB));
            LOAD_ROW(y0, y1, y2, y3, (const float4*)(ctxE + (size_t)r1 * EMB));

            // LDS fragments
            float4 a0, a1, a2, a3, c0, c1, c2, c3, n0, n1, n2, n3;
            LOAD_ROW(a0, a1, a2, a3, (const float4*)sN[sj]);
            LOAD_ROW(c0, c1, c2, c3, (const float4*)sC[dj]);
            LOAD_ROW(n0, n1, n2, n3, (const float4*)sN[dj]);

            // lane-local tree dots (reductions deferred so their DPP/swizzle
            // chains overlap); double-buffer reloads interleaved
            const float dp = DOT16(a0, a1, a2, a3, c0, c1, c2, c3);
            const float d0 = DOT16(n0, n1, n2, n3, x0, x1, x2, x3);
            LOAD_ROW(x0, x1, x2, x3, (const float4*)(ctxE + (size_t)r2 * EMB));
            const float d1 = DOT16(n0, n1, n2, n3, y0, y1, y2, y3);
            LOAD_ROW(y0, y1, y2, y3, (const float4*)(ctxE + (size_t)r3 * EMB));
            const float d2 = DOT16(n0, n1, n2, n3, x0, x1, x2, x3);
            LOAD_ROW(x0, x1, x2, x3, (const float4*)(ctxE + (size_t)r4 * EMB));
            const float d3 = DOT16(n0, n1, n2, n3, y0, y1, y2, y3);
            const float d4 = DOT16(n0, n1, n2, n3, x0, x1, x2, x3);

            // 6 independent group reductions
            const float sp = grp8_sum(dp);
            const float s0 = grp8_sum(d0);
            const float s1 = grp8_sum(d1);
            const float s2 = grp8_sum(d2);
            const float s3 = grp8_sum(d3);
            const float s4 = grp8_sum(d4);

            acc += softplus_fast(-fminf(6.f, fmaxf(-6.f, sp)));
            acc += softplus_fast( fminf(6.f, fmaxf(-6.f, s0)));
            acc += softplus_fast( fminf(6.f, fmaxf(-6.f, s1)));
            acc += softplus_fast( fminf(6.f, fmaxf(-6.f, s2)));
            acc += softplus_fast( fminf(6.f, fmaxf(-6.f, s3)));
            acc += softplus_fast( fminf(6.f, fmaxf(-6.f, s4)));
        }
    }

    // group sums -> wave sum (each group counted once)
    acc += __shfl_xor(acc, 8);
    acc += __shfl_xor(acc, 16);
    acc += __shfl_xor(acc, 32);

    if ((tid & 63) == 0) wsum[tid >> 6] = acc;
    __syncthreads();
    if (tid == 0) {
        float tot = 0.f;
        #pragma unroll
        for (int w = 0; w < THREADS / 64; ++w) tot += wsum[w];
        atomicAdd(out, tot * (1.0f / (float)NPOS));
    }
}

extern "C" void kernel_launch(void* const* d_in, const int* in_sizes, int n_in,
                              void* d_out, int out_size, void* d_ws, size_t ws_size,
                              hipStream_t stream) {
    const int*   walk   = (const int*)d_in[0];
    const int*   negdst = (const int*)d_in[1];
    const float* nodeE  = (const float*)d_in[2];
    const float* ctxE   = (const float*)d_in[3];
    float*       out    = (float*)d_out;

    hipMemsetAsync(out, 0, sizeof(float), stream);
    dw_fused<<<NBLOCKS, THREADS, 0, stream>>>(walk, negdst, nodeE, ctxE, out);
}

// Round 12
// 42.053 us; speedup vs baseline: 1.5598x; 1.5598x over previous
//
#include <hip/hip_runtime.h>

#define WALK_LEN 40
#define WINDOW   5
#define NPAIRS   370
#define BATCHSZ  512
#define NEGK     5
#define NPOS     (BATCHSZ * NPAIRS)        // 189440
#define EMB      128
#define NQ       (BATCHSZ * WALK_LEN)      // 20480 flat-walk rows
#define THREADS  512
#define GROUPS   (THREADS / 8)             // 64 8-lane groups
#define HALFP    185                       // pairs per block (2 blocks/batch)
#define NBLOCKS  (BATCHSZ * 2)             // 1024

struct PairTab { short src[NPAIRS]; short dst[NPAIRS]; };

constexpr PairTab make_pairs() {
    PairTab t{};
    int k = 0;
    for (int i = 0; i < WALK_LEN; ++i) {
        int lo = (i - WINDOW > 0) ? (i - WINDOW) : 0;
        for (int j = lo; j < i; ++j) { t.src[k] = (short)j; t.dst[k] = (short)i; ++k; }
        int hi = (i + 1 + WINDOW < WALK_LEN) ? (i + 1 + WINDOW) : WALK_LEN;
        for (int j = i + 1; j < hi; ++j) { t.src[k] = (short)j; t.dst[k] = (short)i; ++k; }
    }
    return t;
}

__constant__ PairTab g_pairs = make_pairs();

__device__ __forceinline__ unsigned short bf16rn(float f) {
    unsigned u = __float_as_uint(f);
    u += 0x7fffu + ((u >> 16) & 1u);
    return (unsigned short)(u >> 16);
}
// pack two floats -> uint of 2 bf16 (low = first elem, matches dot_pk unpack)
__device__ __forceinline__ unsigned bf16pk(float lo, float hi) {
    return (unsigned)bf16rn(lo) | ((unsigned)bf16rn(hi) << 16);
}

// fast softplus: log(1+e^x); |err| ~1e-7 for x in [-6,6]
__device__ __forceinline__ float softplus_fast(float x) {
    return __logf(1.0f + __expf(x));
}

// 8-lane-group butterfly sum: xor1/xor2 via quad_perm DPP (VALU-only),
// xor4 via one ds_swizzle. (No ds_bpermute.)
template <int CTRL>
__device__ __forceinline__ float dpp_qperm_add(float x) {
    int y = __builtin_amdgcn_update_dpp(0, __float_as_int(x), CTRL, 0xF, 0xF, true);
    return x + __int_as_float(y);
}
__device__ __forceinline__ float grp8_sum(float d) {
    d = dpp_qperm_add<0xB1>(d);    // quad_perm [1,0,3,2] == xor 1
    d = dpp_qperm_add<0x4E>(d);    // quad_perm [2,3,0,1] == xor 2
    int y = __builtin_amdgcn_ds_swizzle(__float_as_int(d), 0x101F); // xor 4
    return d + __int_as_float(y);
}

// unpack uint4 (8 bf16) -> 8 f32 (static indices -> registers)
#define UNPACK_U4(u, f, base)                                         \
    do {                                                              \
        _Pragma("unroll")                                             \
        for (int _i = 0; _i < 4; ++_i) {                              \
            const unsigned _v = (&(u).x)[_i];                         \
            (f)[(base) + 2 * _i]     = __uint_as_float(_v << 16);     \
            (f)[(base) + 2 * _i + 1] = __uint_as_float(_v & 0xffff0000u); \
        }                                                             \
    } while (0)

// dot of pre-unpacked 16 floats against packed bf16 rows xa,xb: 4 fma trees
__device__ __forceinline__ float dot_pk(const float* nf, uint4 xa, uint4 xb) {
    float s0 = 0.f, s1 = 0.f, s2 = 0.f, s3 = 0.f;
    #pragma unroll
    for (int i = 0; i < 4; ++i) {
        const unsigned v = (&xa.x)[i];
        s0 = fmaf(__uint_as_float(v << 16),          nf[2 * i],     s0);
        s1 = fmaf(__uint_as_float(v & 0xffff0000u),  nf[2 * i + 1], s1);
    }
    #pragma unroll
    for (int i = 0; i < 4; ++i) {
        const unsigned v = (&xb.x)[i];
        s2 = fmaf(__uint_as_float(v << 16),          nf[8 + 2 * i],     s2);
        s3 = fmaf(__uint_as_float(v & 0xffff0000u),  nf[8 + 2 * i + 1], s3);
    }
    return (s0 + s1) + (s2 + s3);
}

// ---- phase 1: gather ONLY ctx flat-walk rows into dense bf16 ----
__global__ __launch_bounds__(256) void dw_gather_ctx(
    const int*   __restrict__ walk,
    const float* __restrict__ ctxE,
    unsigned short* __restrict__ dC,
    float* __restrict__ out)
{
    const int idx = blockIdx.x * 256 + threadIdx.x;   // 0 .. NQ*32-1
    if (idx == 0) out[0] = 0.f;
    const int q = idx >> 5, c = idx & 31;
    const int row = walk[q];
    const float4 v = *((const float4*)(ctxE + (size_t)row * EMB) + c);
    ushort4 o;
    o.x = bf16rn(v.x); o.y = bf16rn(v.y); o.z = bf16rn(v.z); o.w = bf16rn(v.w);
    *((ushort4*)(dC + (size_t)q * EMB) + c) = o;
}

// ---- phase 2: one block = half a batch (185 pairs) ----
// sN/sC staged bf16 DIRECTLY from the f32 tables (scattered but tiny);
// neg-dst rows from compact dC (L2-resident). Hot loop == R10.
__global__ __launch_bounds__(THREADS) void dw_score(
    const int* __restrict__ walk,
    const int* __restrict__ negdst,                 // [NPOS*NEGK] -> dense row id
    const float* __restrict__ nodeE,
    const float* __restrict__ ctxE,
    const unsigned short* __restrict__ dC,
    float* __restrict__ out)
{
    __shared__ unsigned int sN[WALK_LEN * 64];      // 10 KB (row = 256 B bf16)
    __shared__ unsigned int sC[WALK_LEN * 64];      // 10 KB
    __shared__ float wsum[THREADS / 64];

    const int b    = blockIdx.x >> 1;
    const int half = blockIdx.x & 1;
    const int tid  = threadIdx.x;

    // stage: u = (r,l); thread loads float4 (elems 4l..4l+3) of walk row r
    // from each table, converts, writes 2 packed uints.
    for (int u = tid; u < WALK_LEN * 32; u += THREADS) {
        const int r = u >> 5, l = u & 31;
        const size_t row = (size_t)walk[b * WALK_LEN + r] * EMB;
        const float4 vn = *((const float4*)(nodeE + row) + l);
        const float4 vc = *((const float4*)(ctxE  + row) + l);
        sN[r * 64 + 2 * l]     = bf16pk(vn.x, vn.y);
        sN[r * 64 + 2 * l + 1] = bf16pk(vn.z, vn.w);
        sC[r * 64 + 2 * l]     = bf16pk(vc.x, vc.y);
        sC[r * 64 + 2 * l + 1] = bf16pk(vc.z, vc.w);
    }
    __syncthreads();

    const int lane8 = tid & 7;
    const int grp   = tid >> 3;           // 0..63
    const int jbase = half * HALFP;
    float acc = 0.0f;

    #pragma unroll 1
    for (int it = 0; it < 3; ++it) {
        const int jj = it * GROUPS + grp;           // 0..191
        if (jj < HALFP) {
            const int j = jbase + jj;
            const int p = b * NPAIRS + j;
            const int sj = g_pairs.src[j];
            const int dj = g_pairs.dst[j];

            const int* nb = negdst + p * NEGK;
            const int q0 = nb[0], q1 = nb[1], q2 = nb[2], q3 = nb[3], q4 = nb[4];

            // issue all 10 neg-row loads up front (MLP)
            const uint4* g0 = (const uint4*)(dC + (size_t)q0 * EMB);
            const uint4* g1 = (const uint4*)(dC + (size_t)q1 * EMB);
            const uint4* g2 = (const uint4*)(dC + (size_t)q2 * EMB);
            const uint4* g3 = (const uint4*)(dC + (size_t)q3 * EMB);
            const uint4* g4 = (const uint4*)(dC + (size_t)q4 * EMB);
            const uint4 x00 = g0[lane8], x01 = g0[lane8 + 8];
            const uint4 x10 = g1[lane8], x11 = g1[lane8 + 8];
            const uint4 x20 = g2[lane8], x21 = g2[lane8 + 8];
            const uint4 x30 = g3[lane8], x31 = g3[lane8 + 8];
            const uint4 x40 = g4[lane8], x41 = g4[lane8 + 8];

            const uint4* rN = (const uint4*)(sN + sj * 64);
            const uint4* rC = (const uint4*)(sC + dj * 64);
            const uint4* rS = (const uint4*)(sN + dj * 64);   // neg src row
            const uint4 a0 = rN[lane8], a1 = rN[lane8 + 8];
            const uint4 c0 = rC[lane8], c1 = rC[lane8 + 8];
            const uint4 n0 = rS[lane8], n1 = rS[lane8 + 8];

            // ---- positive: unpack a once, dot against packed c ----
            {
                float af[16];
                UNPACK_U4(a0, af, 0);
                UNPACK_U4(a1, af, 8);
                float d = grp8_sum(dot_pk(af, c0, c1));
                const float s = fminf(6.f, fmaxf(-6.f, d));
                acc += softplus_fast(-s);
            }

            // ---- negatives: unpack n ONCE, 5 tree-dots against packed x ----
            {
                float nf[16];
                UNPACK_U4(n0, nf, 0);
                UNPACK_U4(n1, nf, 8);
                float d0 = grp8_sum(dot_pk(nf, x00, x01));
                float d1 = grp8_sum(dot_pk(nf, x10, x11));
                float d2 = grp8_sum(dot_pk(nf, x20, x21));
                float d3 = grp8_sum(dot_pk(nf, x30, x31));
                float d4 = grp8_sum(dot_pk(nf, x40, x41));
                acc += softplus_fast(fminf(6.f, fmaxf(-6.f, d0)));
                acc += softplus_fast(fminf(6.f, fmaxf(-6.f, d1)));
                acc += softplus_fast(fminf(6.f, fmaxf(-6.f, d2)));
                acc += softplus_fast(fminf(6.f, fmaxf(-6.f, d3)));
                acc += softplus_fast(fminf(6.f, fmaxf(-6.f, d4)));
            }
        }
    }

    // group sums -> wave sum (each group counted once)
    acc += __shfl_xor(acc, 8);
    acc += __shfl_xor(acc, 16);
    acc += __shfl_xor(acc, 32);

    if ((tid & 63) == 0) wsum[tid >> 6] = acc;
    __syncthreads();
    if (tid == 0) {
        float tot = 0.f;
        #pragma unroll
        for (int w = 0; w < THREADS / 64; ++w) tot += wsum[w];
        atomicAdd(out, tot * (1.0f / (float)NPOS));
    }
}

extern "C" void kernel_launch(void* const* d_in, const int* in_sizes, int n_in,
                              void* d_out, int out_size, void* d_ws, size_t ws_size,
                              hipStream_t stream) {
    const int*   walk   = (const int*)d_in[0];
    const int*   negdst = (const int*)d_in[1];
    const float* nodeE  = (const float*)d_in[2];
    const float* ctxE   = (const float*)d_in[3];
    float*       out    = (float*)d_out;

    unsigned short* dC = (unsigned short*)d_ws;

    dw_gather_ctx<<<(NQ * 32) / 256, 256, 0, stream>>>(walk, ctxE, dC, out);
    dw_score<<<NBLOCKS, THREADS, 0, stream>>>(walk, negdst, nodeE, ctxE, dC, out);
}